// Round 6
// baseline (115.337 us; speedup 1.0000x reference)
//
#include <hip/hip_runtime.h>
#include <stdint.h>

#define D_DIM 128
#define NROW 8192          // 2B
#define L2EPS 1e-12f
#define LOG2E_X10 14.426950408889634f   // 10 / ln(2): exp(s*10) = 2^(s*LOG2E_X10)
#define LN2 0.6931471805599453f

typedef __attribute__((ext_vector_type(8))) short short8;
typedef __attribute__((ext_vector_type(4))) float f32x4;

#define AS1 __attribute__((address_space(1)))
#define AS3 __attribute__((address_space(3)))

static __device__ inline void gload_lds16(const void* g, void* l) {
    __builtin_amdgcn_global_load_lds((const AS1 uint32_t*)g, (AS3 uint32_t*)l, 16, 0, 0);
}

static __device__ inline ushort f2bf(float f) {
    union { float f; uint32_t u; } v; v.f = f;
    uint32_t u = v.u;
    uint32_t r = (u + 0x7fffu + ((u >> 16) & 1u)) >> 16;   // RNE
    return (ushort)r;
}

// K1: L2-normalize rows of [x_i; x_j] -> bf16 z (B operand) and bf16
// z_s = z * 10/ln2 (A operand; makes MFMA output the exp2 argument directly).
__global__ __launch_bounds__(256) void k_normalize(
        const float* __restrict__ xi, const float* __restrict__ xj,
        ushort* __restrict__ z, ushort* __restrict__ z_s,
        float* __restrict__ pos_acc) {
    const int wave = threadIdx.x >> 6;
    const int lane = threadIdx.x & 63;
    const int row = blockIdx.x * 4 + wave;
    const float* src = (row < 4096) ? (xi + (size_t)row * D_DIM)
                                    : (xj + (size_t)(row - 4096) * D_DIM);
    float2 v = *(const float2*)(src + lane * 2);
    float ss = v.x * v.x + v.y * v.y;
#pragma unroll
    for (int m = 32; m >= 1; m >>= 1) ss += __shfl_xor(ss, m, 64);
    const float scale = 1.0f / fmaxf(sqrtf(ss), L2EPS);
    const float scale_s = scale * LOG2E_X10;
    ushort2 o, os;
    o.x  = f2bf(v.x * scale);    o.y  = f2bf(v.y * scale);
    os.x = f2bf(v.x * scale_s);  os.y = f2bf(v.y * scale_s);
    *(ushort2*)(z   + (size_t)row * D_DIM + lane * 2) = o;
    *(ushort2*)(z_s + (size_t)row * D_DIM + lane * 2) = os;

    if (blockIdx.x == 0 && threadIdx.x == 0) pos_acc[0] = 0.0f;
}

// K2: block (rb=bid>>4, cc=bid&15) computes sim*10/ln2 for rows
// [rb*128,+128) x cols [cc*512,+512). A band (scaled z_s) staged once into
// the 32 KB LDS (XOR swizzle), fragments hoisted to registers; the same
// 32 KB is then reused as the B double-buffer (2 x 16 KB), streamed as 8
// tiles of 64x128 via global_load_lds with prefetch. Epilogue per element:
// v_exp + v_add only. Row partials -> denom_part[cc][row], single writer.
// 1024 blocks -> 4 resident blocks/CU (32 KB LDS), 16 waves/CU.
__global__ __launch_bounds__(256, 2) void k_gemm(
        const ushort* __restrict__ z, const ushort* __restrict__ z_s,
        float* __restrict__ denom_part, float* __restrict__ pos_acc) {
    __shared__ __align__(16) ushort lds[2][64 * 128];   // 32 KB total (aliased)
    ushort* flat = (ushort*)lds;

    const int bid = blockIdx.x;
    const int t = threadIdx.x;
    const int wave = t >> 6, lane = t & 63;
    const int quad = lane >> 4, lc = lane & 15;

    const int rb = bid >> 4;            // row band 0..63 (128 rows)
    const int cc = bid & 15;            // col chunk 0..15 (512 cols)
    const int rowbase = rb * 128;
    const int colbase = cc * 512;

    // Per-lane DMA addressing, hoisted out of the loop.
    uint32_t goff[4];
    ushort* ldst[2][4];
#pragma unroll
    for (int q = 0; q < 4; q++) {
        const int s = q * 256 + t;
        const int r = s >> 4;
        const int gc = (s & 15) ^ (r & 15);
        goff[q] = (uint32_t)r * D_DIM + gc * 8;
        ldst[0][q] = &lds[0][s * 8];
        ldst[1][q] = &lds[1][s * 8];
    }

    // Stage A band: 128 rows of z_s (contiguous 32 KB), XOR swizzle
    // (16B chunk g of row r lands at slot g ^ (r&15)).
    {
        const ushort* za = z_s + (size_t)rowbase * D_DIM;
#pragma unroll
        for (int q = 0; q < 8; q++) {
            const int s = q * 256 + t;
            const int r = s >> 4;
            const int gc = (s & 15) ^ (r & 15);
            gload_lds16(za + (size_t)r * D_DIM + gc * 8, &flat[s * 8]);
        }
        asm volatile("s_waitcnt vmcnt(0)" ::: "memory");
        __syncthreads();
    }

    // Hoist A fragments: wave owns rows [wave*32, +32): 2 row-tiles x 4 K-chunks.
    short8 afr[2][4];
#pragma unroll
    for (int i = 0; i < 2; i++)
#pragma unroll
        for (int k = 0; k < 4; k++)
            afr[i][k] = *(const short8*)
                &flat[(wave * 32 + i * 16 + lc) * D_DIM + ((k * 4 + quad) ^ lc) * 8];
    __syncthreads();   // all A reads done before B0 DMA overwrites this LDS

    // First B tile into buffer 0.
    {
        const ushort* zb = z + (size_t)colbase * D_DIM;
#pragma unroll
        for (int q = 0; q < 4; q++)
            gload_lds16(zb + goff[q], ldst[0][q]);
        asm volatile("s_waitcnt vmcnt(0)" ::: "memory");
        __syncthreads();
    }

    const bool diagblk = (cc == (rb >> 2));
    const bool posblk  = (cc == ((rb ^ 32) >> 2));
    const int diag_it2 = rb & 3;
    const int pos_it2  = (rb ^ 32) & 3;

    float rs[2][4] = {{0.f,0.f,0.f,0.f},{0.f,0.f,0.f,0.f}};
    float posp = 0.f;
    const int rgbase = rowbase + wave * 32 + quad * 4;   // + i*16 + r

    for (int it = 0; it < 8; it++) {
        const int cur = it & 1;
        if (it < 7) {  // prefetch next B tile into the other buffer
            const ushort* zb = z + (size_t)(colbase + (it + 1) * 64) * D_DIM;
#pragma unroll
            for (int q = 0; q < 4; q++)
                gload_lds16(zb + goff[q], ldst[cur ^ 1][q]);
        }

        f32x4 acc[2][4];
#pragma unroll
        for (int i = 0; i < 2; i++)
#pragma unroll
            for (int j = 0; j < 4; j++) acc[i][j] = (f32x4){0.f, 0.f, 0.f, 0.f};

#pragma unroll
        for (int j = 0; j < 4; j++) {
            short8 bfr[4];
#pragma unroll
            for (int k = 0; k < 4; k++)
                bfr[k] = *(const short8*)
                    &lds[cur][(j * 16 + lc) * D_DIM + ((k * 4 + quad) ^ lc) * 8];
#pragma unroll
            for (int k = 0; k < 4; k++) {
                acc[0][j] = __builtin_amdgcn_mfma_f32_16x16x32_bf16(afr[0][k], bfr[k], acc[0][j], 0, 0, 0);
                acc[1][j] = __builtin_amdgcn_mfma_f32_16x16x32_bf16(afr[1][k], bfr[k], acc[1][j], 0, 0, 0);
            }
        }

        const bool dit = diagblk && ((it >> 1) == diag_it2);
        const bool pit = posblk && ((it >> 1) == pos_it2);
        if (dit || pit) {   // careful path: <= 2 of 8 iters, <= 1/8 of blocks
#pragma unroll
            for (int i = 0; i < 2; i++)
#pragma unroll
                for (int j = 0; j < 4; j++)
#pragma unroll
                    for (int r = 0; r < 4; r++) {
                        const float s = acc[i][j][r];   // scaled sim
                        float e = exp2f(s);
                        const int rg = rgbase + i * 16 + r;
                        const int cg = colbase + it * 64 + j * 16 + lc;
                        if (dit && rg == cg) e = 0.f;            // exclude diag
                        if (pit && cg == (rg ^ 4096)) posp += s; // positive (scaled)
                        rs[i][r] += e;
                    }
        } else {            // hot path: exp + accumulate only
#pragma unroll
            for (int i = 0; i < 2; i++)
#pragma unroll
                for (int j = 0; j < 4; j++)
#pragma unroll
                    for (int r = 0; r < 4; r++)
                        rs[i][r] += exp2f(acc[i][j][r]);
        }

        asm volatile("s_waitcnt vmcnt(0)" ::: "memory");
        __syncthreads();
    }

    // Row partials: reduce over the 16 col-lanes, one store per row.
#pragma unroll
    for (int i = 0; i < 2; i++)
#pragma unroll
        for (int r = 0; r < 4; r++) {
            float v = rs[i][r];
            v += __shfl_xor(v, 1, 64);
            v += __shfl_xor(v, 2, 64);
            v += __shfl_xor(v, 4, 64);
            v += __shfl_xor(v, 8, 64);
            if (lc == 0)
                denom_part[(size_t)cc * NROW + rgbase + i * 16 + r] = v;
        }

    if (posblk) {
#pragma unroll
        for (int m = 32; m >= 1; m >>= 1) posp += __shfl_xor(posp, m, 64);
        if (lane == 0) atomicAdd(pos_acc, posp);
    }
}

// K3 (fused logsum+combine): one block, 1024 threads; each thread owns 8 rows.
// pos_acc holds sum of (sim*10/ln2) over positives -> *ln2 gives sum(sim*10).
__global__ __launch_bounds__(1024) void k_logsum(
        const float* __restrict__ denom_part, const float* __restrict__ pos_acc,
        float* __restrict__ out) {
    __shared__ float red[16];
    const int t = threadIdx.x;
    float v = 0.f;
#pragma unroll
    for (int rr = 0; rr < 8; rr++) {
        const int row = rr * 1024 + t;
        float d = 0.f;
#pragma unroll
        for (int p = 0; p < 16; p++) d += denom_part[(size_t)p * NROW + row];
        v += __logf(d);
    }
#pragma unroll
    for (int m = 32; m >= 1; m >>= 1) v += __shfl_xor(v, m, 64);
    if ((t & 63) == 0) red[t >> 6] = v;
    __syncthreads();
    if (t == 0) {
        float total = 0.f;
#pragma unroll
        for (int i = 0; i < 16; i++) total += red[i];
        out[0] = (total - pos_acc[0] * LN2) / (float)NROW;
    }
}

extern "C" void kernel_launch(void* const* d_in, const int* in_sizes, int n_in,
                              void* d_out, int out_size, void* d_ws, size_t ws_size,
                              hipStream_t stream) {
    const float* xi = (const float*)d_in[0];
    const float* xj = (const float*)d_in[1];
    ushort* z   = (ushort*)d_ws;                                 // 2 MB bf16
    ushort* z_s = z + (size_t)NROW * D_DIM;                      // 2 MB bf16 (scaled)
    float* denom_part = (float*)(z_s + (size_t)NROW * D_DIM);    // 16 x 8192 f32
    float* pos_acc = denom_part + 16 * NROW;
    float* out = (float*)d_out;

    hipLaunchKernelGGL(k_normalize, dim3(NROW / 4), dim3(256), 0, stream,
                       xi, xj, z, z_s, pos_acc);
    hipLaunchKernelGGL(k_gemm, dim3(1024), dim3(256), 0, stream,
                       z, z_s, denom_part, pos_acc);
    hipLaunchKernelGGL(k_logsum, dim3(1), dim3(1024), 0, stream,
                       denom_part, pos_acc, out);
}